// Round 13
// baseline (171.519 us; speedup 1.0000x reference)
//
#include <hip/hip_runtime.h>
#include <stddef.h>

typedef unsigned short u16;
typedef float f32x4 __attribute__((ext_vector_type(4)));
typedef __bf16 bf16x8 __attribute__((ext_vector_type(8)));
typedef unsigned int u32;
typedef u32 u32x2 __attribute__((ext_vector_type(2)));

#define NNODES 6144
#define NUMS   3072
#define DIM    256
#define PPERS  4
#define KG     1024   /* P*DIM */
#define NHID   256
#define OFEAT  128

__device__ __forceinline__ u16 f2b(float f) {
  unsigned u = __float_as_uint(f);
  unsigned r = u + 0x7fffu + ((u >> 16) & 1u);   // RNE f32->bf16 (finite inputs)
  return (u16)(r >> 16);
}
__device__ __forceinline__ float b2f_lo(u32 v) { return __uint_as_float((v & 0xffffu) << 16); }
__device__ __forceinline__ float b2f_hi(u32 v) { return __uint_as_float((v >> 16) << 16); }

__device__ __forceinline__ void gload16(const void* g, void* l) {
  __builtin_amdgcn_global_load_lds((__attribute__((address_space(1))) void*)g,
                                   (__attribute__((address_space(3))) void*)l,
                                   16, 0, 0);
}

// ---------------------------------------------------------------------------
// Build G[n, p*256+d] = 0.5*(emb*glw_p)/||emb*glw_p||, EMB bf16 copy,
// + fused weight transposes (blocks < 256) and RSUM zeroing (blocks < 24).
// ---------------------------------------------------------------------------
__global__ void build_g(const float* __restrict__ stru, const float* __restrict__ mm,
                        const float* __restrict__ glw, const float* __restrict__ w0,
                        const float* __restrict__ w1, u16* __restrict__ G,
                        u16* __restrict__ EMB, u16* __restrict__ W0T,
                        u16* __restrict__ W1T, float* __restrict__ RSUM) {
  const int n = blockIdx.x;
  const int d = threadIdx.x;
  if (n < NHID)  W0T[n * DIM + d] = f2b(w0[(size_t)d * NHID + n]);
  if (n < OFEAT) W1T[n * DIM + d] = f2b(w1[(size_t)d * OFEAT + n]);
  if (n < 24)    RSUM[n * 256 + d] = 0.0f;

  const float* src = (n < NUMS) ? (stru + (size_t)n * DIM) : (mm + (size_t)(n - NUMS) * DIM);
  float e = src[d];
  EMB[(size_t)n * DIM + d] = f2b(e);
  __shared__ float red[16];
  float y[PPERS];
#pragma unroll
  for (int p = 0; p < PPERS; ++p) {
    y[p] = e * glw[p * DIM + d];
    float s = y[p] * y[p];
#pragma unroll
    for (int o = 32; o; o >>= 1) s += __shfl_xor(s, o);
    if ((d & 63) == 0) red[p * 4 + (d >> 6)] = s;
  }
  __syncthreads();
#pragma unroll
  for (int p = 0; p < PPERS; ++p) {
    float tot = red[p * 4 + 0] + red[p * 4 + 1] + red[p * 4 + 2] + red[p * 4 + 3];
    float inv = 0.5f / fmaxf(sqrtf(tot), 1e-12f);
    G[(size_t)n * KG + p * DIM + d] = f2b(y[p] * inv);
  }
}

// ---------------------------------------------------------------------------
// Merged kernel: blocks < 1176 -> symmetric Gram GEMM, NO rowsum (moved to
// hop1); blocks >= 1176 -> the 96-block X0T weight GEMM. Dual write of sym
// tiles (direct + LDS-transposed, 136-stride pad).
// ---------------------------------------------------------------------------
__global__ __launch_bounds__(256, 2)
void gemm_sym_x0(const u16* __restrict__ G, const u16* __restrict__ EMB,
                 const u16* __restrict__ W0T, u16* __restrict__ ADJ,
                 u16* __restrict__ X0T) {
  __shared__ __align__(16) u16 SMEM[128 * 136];
  u16* As = SMEM;
  u16* Bs = SMEM + 128 * 64;

  const int tid = threadIdx.x;
  const int lane = tid & 63;
  const int wv = tid >> 6;
  const int wr = wv >> 1, wc = wv & 1;
  const int lrow = lane & 15, kg = lane >> 4;

  f32x4 acc[4][4];
  const f32x4 zero = {0.f, 0.f, 0.f, 0.f};
#pragma unroll
  for (int i = 0; i < 4; ++i)
#pragma unroll
    for (int j = 0; j < 4; ++j) acc[i][j] = zero;

  if (blockIdx.x >= 1176) {
    // ---- X0T path: X0T[j][node] = sum_d W0T[j][d]*EMB[node][d], K=256 ----
    int u = blockIdx.x - 1176;
    const int m0 = (u / 48) * 128;
    const int n0 = (u % 48) * 128;
    for (int kt = 0; kt < DIM; kt += 64) {
      __syncthreads();
#pragma unroll
      for (int i = 0; i < 4; ++i) {
        int pos = i * 256 + wv * 64 + lane;
        int r = pos >> 3;
        int c = (pos & 7) * 8;
        int dstOff = (i * 256 + wv * 64) * 16;
        gload16(W0T + (size_t)(m0 + r) * DIM + kt + c, (char*)As + dstOff);
        gload16(EMB + (size_t)(n0 + r) * DIM + kt + c, (char*)Bs + dstOff);
      }
      __syncthreads();
#pragma unroll
      for (int kk = 0; kk < 2; ++kk) {
        bf16x8 a[4], b[4];
#pragma unroll
        for (int mi = 0; mi < 4; ++mi)
          a[mi] = *(const bf16x8*)&As[(wr * 64 + mi * 16 + lrow) * 64 + kk * 32 + kg * 8];
#pragma unroll
        for (int ni = 0; ni < 4; ++ni)
          b[ni] = *(const bf16x8*)&Bs[(wc * 64 + ni * 16 + lrow) * 64 + kk * 32 + kg * 8];
#pragma unroll
        for (int mi = 0; mi < 4; ++mi)
#pragma unroll
          for (int ni = 0; ni < 4; ++ni)
            acc[mi][ni] = __builtin_amdgcn_mfma_f32_16x16x32_bf16(a[mi], b[ni], acc[mi][ni], 0, 0, 0);
      }
    }
#pragma unroll
    for (int mi = 0; mi < 4; ++mi)
#pragma unroll
      for (int r = 0; r < 4; ++r) {
        int row = m0 + wr * 64 + mi * 16 + kg * 4 + r;
        size_t base = (size_t)row * NNODES;
#pragma unroll
        for (int ni = 0; ni < 4; ++ni) {
          int col = n0 + wc * 64 + ni * 16 + lrow;
          X0T[base + col] = f2b(acc[mi][ni][r]);
        }
      }
    return;
  }

  // ---- sym path ----
  int t = blockIdx.x;
  t = (t & 7) * 147 + (t >> 3);          // 1176 = 8 * 147, bijective XCD swizzle
  int rT = (int)((sqrtf(8.0f * (float)t + 1.0f) - 1.0f) * 0.5f);
  while ((rT + 1) * (rT + 2) / 2 <= t) ++rT;
  while (rT * (rT + 1) / 2 > t) --rT;
  const int cT = t - rT * (rT + 1) / 2;
  const int m0 = rT * 128;
  const int n0 = cT * 128;
  const bool diag = (rT == cT);

  for (int kt = 0; kt < KG; kt += 64) {
    __syncthreads();
#pragma unroll
    for (int i = 0; i < 4; ++i) {
      int pos = i * 256 + wv * 64 + lane;
      int r = pos >> 3;
      int c = (pos & 7) * 8;
      int dstOff = (i * 256 + wv * 64) * 16;
      gload16(G + (size_t)(m0 + r) * KG + kt + c, (char*)As + dstOff);
      gload16(G + (size_t)(n0 + r) * KG + kt + c, (char*)Bs + dstOff);
    }
    __syncthreads();
#pragma unroll
    for (int kk = 0; kk < 2; ++kk) {
      bf16x8 a[4], b[4];
#pragma unroll
      for (int mi = 0; mi < 4; ++mi)
        a[mi] = *(const bf16x8*)&As[(wr * 64 + mi * 16 + lrow) * 64 + kk * 32 + kg * 8];
#pragma unroll
      for (int ni = 0; ni < 4; ++ni)
        b[ni] = *(const bf16x8*)&Bs[(wc * 64 + ni * 16 + lrow) * 64 + kk * 32 + kg * 8];
#pragma unroll
      for (int mi = 0; mi < 4; ++mi)
#pragma unroll
        for (int ni = 0; ni < 4; ++ni)
          acc[mi][ni] = __builtin_amdgcn_mfma_f32_16x16x32_bf16(a[mi], b[ni], acc[mi][ni], 0, 0, 0);
    }
  }

  __syncthreads();   // K-loop fully done before SMEM reuse as T-buffer

  // relu in place
#pragma unroll
  for (int mi = 0; mi < 4; ++mi)
#pragma unroll
    for (int ni = 0; ni < 4; ++ni)
#pragma unroll
      for (int r = 0; r < 4; ++r) acc[mi][ni][r] = fmaxf(acc[mi][ni][r], 0.0f);

  // direct store + transpose pack (no rowsums here — hop1 computes them)
#pragma unroll
  for (int mi = 0; mi < 4; ++mi) {
#pragma unroll
    for (int r = 0; r < 4; ++r) {
      int row = m0 + wr * 64 + mi * 16 + kg * 4 + r;
      size_t base = (size_t)row * NNODES;
#pragma unroll
      for (int ni = 0; ni < 4; ++ni) {
        int col = n0 + wc * 64 + ni * 16 + lrow;
        ADJ[base + col] = f2b(acc[mi][ni][r]);
      }
    }
    if (!diag) {
#pragma unroll
      for (int ni = 0; ni < 4; ++ni) {
        int cl = wc * 64 + ni * 16 + lrow;
        int rl0 = wr * 64 + mi * 16 + kg * 4;
        u32x2 pack;
        pack[0] = (u32)f2b(acc[mi][ni][0]) | ((u32)f2b(acc[mi][ni][1]) << 16);
        pack[1] = (u32)f2b(acc[mi][ni][2]) | ((u32)f2b(acc[mi][ni][3]) << 16);
        *(u32x2*)&SMEM[cl * 136 + rl0] = pack;
      }
    }
  }

  if (!diag) {
    __syncthreads();
#pragma unroll
    for (int it = 0; it < 8; ++it) {
      int cid = it * 256 + tid;
      int rr = cid >> 4;
      int c8 = (cid & 15) * 8;
      bf16x8 v = *(const bf16x8*)&SMEM[rr * 136 + c8];
      *(bf16x8*)&ADJ[(size_t)(n0 + rr) * NNODES + m0 + c8] = v;
    }
  }
}

// ---------------------------------------------------------------------------
// NT bf16 GEMM 128x128 -> bf16 store (HW1T weight GEMM).
// ---------------------------------------------------------------------------
__global__ __launch_bounds__(256, 2)
void gemm_nt(const u16* __restrict__ A, const u16* __restrict__ B, u16* __restrict__ C,
             int N, int ldA, int ldB, int K) {
  __shared__ __align__(16) u16 As[128 * 64];
  __shared__ __align__(16) u16 Bs[128 * 64];
  const int tid = threadIdx.x;
  const int lane = tid & 63;
  const int wv = tid >> 6;
  const int m0 = blockIdx.y * 128;
  const int n0 = blockIdx.x * 128;
  const int wr = wv >> 1, wc = wv & 1;
  const int lrow = lane & 15, kg = lane >> 4;

  f32x4 acc[4][4];
  const f32x4 zero = {0.f, 0.f, 0.f, 0.f};
#pragma unroll
  for (int i = 0; i < 4; ++i)
#pragma unroll
    for (int j = 0; j < 4; ++j) acc[i][j] = zero;

  for (int kt = 0; kt < K; kt += 64) {
    __syncthreads();
#pragma unroll
    for (int i = 0; i < 4; ++i) {
      int pos = i * 256 + wv * 64 + lane;
      int r = pos >> 3;
      int c = (pos & 7) * 8;
      int dstOff = (i * 256 + wv * 64) * 16;
      gload16(A + (size_t)(m0 + r) * ldA + kt + c, (char*)As + dstOff);
      gload16(B + (size_t)(n0 + r) * ldB + kt + c, (char*)Bs + dstOff);
    }
    __syncthreads();
#pragma unroll
    for (int kk = 0; kk < 2; ++kk) {
      bf16x8 a[4], b[4];
#pragma unroll
      for (int mi = 0; mi < 4; ++mi)
        a[mi] = *(const bf16x8*)&As[(wr * 64 + mi * 16 + lrow) * 64 + kk * 32 + kg * 8];
#pragma unroll
      for (int ni = 0; ni < 4; ++ni)
        b[ni] = *(const bf16x8*)&Bs[(wc * 64 + ni * 16 + lrow) * 64 + kk * 32 + kg * 8];
#pragma unroll
      for (int mi = 0; mi < 4; ++mi)
#pragma unroll
        for (int ni = 0; ni < 4; ++ni)
          acc[mi][ni] = __builtin_amdgcn_mfma_f32_16x16x32_bf16(a[mi], b[ni], acc[mi][ni], 0, 0, 0);
    }
  }

#pragma unroll
  for (int mi = 0; mi < 4; ++mi)
#pragma unroll
    for (int r = 0; r < 4; ++r) {
      int row = m0 + wr * 64 + mi * 16 + kg * 4 + r;
      size_t base = (size_t)row * N;
#pragma unroll
      for (int ni = 0; ni < 4; ++ni) {
        int col = n0 + wc * 64 + ni * 16 + lrow;
        C[base + col] = f2b(acc[mi][ni][r]);
      }
    }
}

// ---------------------------------------------------------------------------
// hop1 GEMM: 64x256 tile, 4 waves in 1x4. A staged via gload_lds (8 KB LDS);
// B (X0T, L2-resident 3.1 MB) loaded DIRECTLY from global into registers —
// no Bs staging, no 32KB LDS, barrier drains only the A-stage.
// grid = (1, M/64, z). Partials: bf16 slices. Atomic fallback: f32.
// + FUSED ADJ ROWSUM from staged As.
// ---------------------------------------------------------------------------
template <bool ATOMIC>
__global__ __launch_bounds__(256, 4)
void gemm_hop1(const u16* __restrict__ A, const u16* __restrict__ Bg, void* __restrict__ Cv,
               float* __restrict__ RSUM, int ldA, int ldB, int kPerSplit, size_t sliceElems) {
  __shared__ __align__(16) u16 As[64 * 64];     // 8 KB
  const int tid = threadIdx.x;
  const int lane = tid & 63;
  const int wv = tid >> 6;
  const int m0 = blockIdx.y * 64;
  const int kBeg = blockIdx.z * kPerSplit;
  const int kEnd = kBeg + kPerSplit;
  const int lrow = lane & 15, kg = lane >> 4;

  f32x4 acc[4][4];
  const f32x4 zero = {0.f, 0.f, 0.f, 0.f};
#pragma unroll
  for (int i = 0; i < 4; ++i)
#pragma unroll
    for (int j = 0; j < 4; ++j) acc[i][j] = zero;

  float rs = 0.f;   // rowsum partial for row m0 + (tid>>2), quarter tid&3

  for (int kt = kBeg; kt < kEnd; kt += 64) {
    __syncthreads();
#pragma unroll
    for (int i = 0; i < 2; ++i) {   // A: 64 rows x 64 cols
      int pos = i * 256 + wv * 64 + lane;
      int r = pos >> 3;
      int c = (pos & 7) * 8;
      int dstOff = (i * 256 + wv * 64) * 16;
      gload16(A + (size_t)(m0 + r) * ldA + kt + c, (char*)As + dstOff);
    }
    __syncthreads();
    // fused rowsum: thread sums 16 staged ADJ values of row tid>>2
    {
      const u32* rowp = (const u32*)&As[(tid >> 2) * 64 + (tid & 3) * 16];
      float s = 0.f;
#pragma unroll
      for (int j = 0; j < 8; ++j) { u32 v = rowp[j]; s += b2f_lo(v) + b2f_hi(v); }
      rs += s;
    }
#pragma unroll
    for (int kk = 0; kk < 2; ++kk) {
      bf16x8 a[4], b[4];
#pragma unroll
      for (int mi = 0; mi < 4; ++mi)
        a[mi] = *(const bf16x8*)&As[(mi * 16 + lrow) * 64 + kk * 32 + kg * 8];
#pragma unroll
      for (int ni = 0; ni < 4; ++ni)
        b[ni] = *(const bf16x8*)&Bg[(size_t)(wv * 64 + ni * 16 + lrow) * ldB + kt + kk * 32 + kg * 8];
#pragma unroll
      for (int mi = 0; mi < 4; ++mi)
#pragma unroll
        for (int ni = 0; ni < 4; ++ni)
          acc[mi][ni] = __builtin_amdgcn_mfma_f32_16x16x32_bf16(a[mi], b[ni], acc[mi][ni], 0, 0, 0);
    }
  }

  // rowsum: combine the 4 quarter-sums of each row (lanes differ in bits 0-1)
  rs += __shfl_xor(rs, 1);
  rs += __shfl_xor(rs, 2);
  if ((tid & 3) == 0) atomicAdd(&RSUM[m0 + (tid >> 2)], rs);

#pragma unroll
  for (int mi = 0; mi < 4; ++mi)
#pragma unroll
    for (int r = 0; r < 4; ++r) {
      int row = m0 + mi * 16 + kg * 4 + r;
      size_t base = (size_t)row * NHID;
#pragma unroll
      for (int ni = 0; ni < 4; ++ni) {
        int col = wv * 64 + ni * 16 + lrow;
        if (ATOMIC) atomicAdd(&((float*)Cv)[base + col], acc[mi][ni][r]);
        else ((u16*)Cv)[(size_t)blockIdx.z * sliceElems + base + col] = f2b(acc[mi][ni][r]);
      }
    }
}

// ---------------------------------------------------------------------------
// hop2 GEMM: 128x128 tile, split-K. A staged (16 KB LDS); B (HW1T, L2-resident
// 1.6 MB) loaded directly from global into registers. grid = (1, M/128, z).
// Partials: bf16 slices. Atomic fallback: f32.
// ---------------------------------------------------------------------------
template <bool ATOMIC>
__global__ __launch_bounds__(256, 4)
void gemm_hop2(const u16* __restrict__ A, const u16* __restrict__ Bg, void* __restrict__ Cv,
               int ldA, int ldB, int kPerSplit, size_t sliceElems) {
  __shared__ __align__(16) u16 As[128 * 64];    // 16 KB
  const int tid = threadIdx.x;
  const int lane = tid & 63;
  const int wv = tid >> 6;
  const int m0 = blockIdx.y * 128;
  const int kBeg = blockIdx.z * kPerSplit;
  const int kEnd = kBeg + kPerSplit;
  const int wr = wv >> 1, wc = wv & 1;
  const int lrow = lane & 15, kg = lane >> 4;

  f32x4 acc[4][4];
  const f32x4 zero = {0.f, 0.f, 0.f, 0.f};
#pragma unroll
  for (int i = 0; i < 4; ++i)
#pragma unroll
    for (int j = 0; j < 4; ++j) acc[i][j] = zero;

  for (int kt = kBeg; kt < kEnd; kt += 64) {
    __syncthreads();
#pragma unroll
    for (int i = 0; i < 4; ++i) {
      int pos = i * 256 + wv * 64 + lane;
      int r = pos >> 3;
      int c = (pos & 7) * 8;
      int dstOff = (i * 256 + wv * 64) * 16;
      gload16(A + (size_t)(m0 + r) * ldA + kt + c, (char*)As + dstOff);
    }
    __syncthreads();
#pragma unroll
    for (int kk = 0; kk < 2; ++kk) {
      bf16x8 a[4], b[4];
#pragma unroll
      for (int mi = 0; mi < 4; ++mi)
        a[mi] = *(const bf16x8*)&As[(wr * 64 + mi * 16 + lrow) * 64 + kk * 32 + kg * 8];
#pragma unroll
      for (int ni = 0; ni < 4; ++ni)
        b[ni] = *(const bf16x8*)&Bg[(size_t)(wc * 64 + ni * 16 + lrow) * ldB + kt + kk * 32 + kg * 8];
#pragma unroll
      for (int mi = 0; mi < 4; ++mi)
#pragma unroll
        for (int ni = 0; ni < 4; ++ni)
          acc[mi][ni] = __builtin_amdgcn_mfma_f32_16x16x32_bf16(a[mi], b[ni], acc[mi][ni], 0, 0, 0);
    }
  }

#pragma unroll
  for (int mi = 0; mi < 4; ++mi)
#pragma unroll
    for (int r = 0; r < 4; ++r) {
      int row = m0 + wr * 64 + mi * 16 + kg * 4 + r;
      size_t base = (size_t)row * OFEAT;
#pragma unroll
      for (int ni = 0; ni < 4; ++ni) {
        int col = wc * 64 + ni * 16 + lrow;
        if (ATOMIC) atomicAdd(&((float*)Cv)[base + col], acc[mi][ni][r]);
        else ((u16*)Cv)[(size_t)blockIdx.z * sliceElems + base + col] = f2b(acc[mi][ni][r]);
      }
    }
}

// reduce1: H[n][j] = bf16(relu( (sum_s P1[s][n][j]) / rowsum[n] + b0[j] ))
template <bool BF16P>
__global__ void reduce1(const void* __restrict__ P1v, int z, const float* __restrict__ RSUM,
                        const float* __restrict__ b0, u16* __restrict__ H) {
  const int tid = threadIdx.x;
  const int n = blockIdx.x * 2 + (tid >> 7);
  const int j0 = (tid & 127) * 2;
  float s0 = 0.f, s1 = 0.f;
  if (BF16P) {
    const u16* P = (const u16*)P1v;
    for (int s = 0; s < z; ++s) {
      u32 v = *(const u32*)&P[((size_t)s * NNODES + n) * NHID + j0];
      s0 += b2f_lo(v); s1 += b2f_hi(v);
    }
  } else {
    const float* P = (const float*)P1v;
    s0 = P[(size_t)n * NHID + j0];
    s1 = P[(size_t)n * NHID + j0 + 1];
  }
  float inv = 1.0f / fmaxf(RSUM[n], 1e-12f);
  float h0 = fmaxf(s0 * inv + b0[j0], 0.f);
  float h1 = fmaxf(s1 * inv + b0[j0 + 1], 0.f);
  *(u32*)&H[(size_t)n * NHID + j0] = (u32)f2b(h0) | ((u32)f2b(h1) << 16);
}

// reduce2: out[n][j] = log_softmax_j( (sum_s P2[s][n][j]) / rowsum[n] + b1[j] )
template <bool BF16P>
__global__ void reduce2(const void* __restrict__ P2v, int z, const float* __restrict__ RSUM,
                        const float* __restrict__ b1, float* __restrict__ out) {
  const int tid = threadIdx.x;
  const int n = blockIdx.x * 4 + (tid >> 6);
  const int j0 = (tid & 63) * 2;
  float s0 = 0.f, s1 = 0.f;
  if (BF16P) {
    const u16* P = (const u16*)P2v;
    for (int s = 0; s < z; ++s) {
      u32 v = *(const u32*)&P[((size_t)s * NNODES + n) * OFEAT + j0];
      s0 += b2f_lo(v); s1 += b2f_hi(v);
    }
  } else {
    const float* P = (const float*)P2v;
    s0 = P[(size_t)n * OFEAT + j0];
    s1 = P[(size_t)n * OFEAT + j0 + 1];
  }
  float inv = 1.0f / fmaxf(RSUM[n], 1e-12f);
  float x0 = s0 * inv + b1[j0];
  float x1 = s1 * inv + b1[j0 + 1];
  float m = fmaxf(x0, x1);
#pragma unroll
  for (int o = 32; o; o >>= 1) m = fmaxf(m, __shfl_xor(m, o));
  float e = expf(x0 - m) + expf(x1 - m);
#pragma unroll
  for (int o = 32; o; o >>= 1) e += __shfl_xor(e, o);
  float lse = m + logf(e);
  out[(size_t)n * OFEAT + j0]     = x0 - lse;
  out[(size_t)n * OFEAT + j0 + 1] = x1 - lse;
}

extern "C" void kernel_launch(void* const* d_in, const int* in_sizes, int n_in,
                              void* d_out, int out_size, void* d_ws, size_t ws_size,
                              hipStream_t stream) {
  const float* stru = (const float*)d_in[0];
  const float* mm   = (const float*)d_in[1];
  const float* glw  = (const float*)d_in[2];
  const float* w0   = (const float*)d_in[3];
  const float* b0   = (const float*)d_in[4];
  const float* w1   = (const float*)d_in[5];
  const float* b1   = (const float*)d_in[6];
  float* out = (float*)d_out;

  char* ws = (char*)d_ws;
  size_t off = 0;
  auto carve = [&](size_t bytes) -> void* {
    void* p = ws + off;
    off += (bytes + 255) & ~(size_t)255;
    return p;
  };
  u16*   G     = (u16*)carve((size_t)NNODES * KG * 2);        // 12.6 MB
  u16*   EMB   = (u16*)carve((size_t)NNODES * DIM * 2);       // 3.1 MB
  u16*   W0T   = (u16*)carve((size_t)NHID * DIM * 2);
  u16*   W1T   = (u16*)carve((size_t)OFEAT * DIM * 2);
  u16*   ADJ   = (u16*)carve((size_t)NNODES * NNODES * 2);    // 75.5 MB
  u16*   X0T   = (u16*)carve((size_t)NHID * NNODES * 2);      // 3.1 MB
  u16*   H     = (u16*)carve((size_t)NNODES * NHID * 2);      // 3.1 MB
  u16*   HW1T  = (u16*)carve((size_t)OFEAT * NNODES * 2);     // 1.6 MB
  float* RSUM  = (float*)carve((size_t)NNODES * 4);           // 24 KB

  // remaining workspace -> bf16 split-K partial slices
  const size_t slice1b = (size_t)NNODES * NHID * 2;   // 3.15 MB (bf16)
  const size_t slice2b = (size_t)NNODES * OFEAT * 2;  // 1.57 MB (bf16)
  size_t avail = (ws_size > off) ? (ws_size - off) : 0;
  char* P = ws + off;

  const int zc1[6] = {8, 6, 4, 3, 2, 1};
  const int zc2[8] = {16, 12, 8, 6, 4, 3, 2, 1};
  int z1 = 1, z2 = 1;
  for (int i = 0; i < 6; ++i) if ((size_t)zc1[i] * slice1b <= avail) { z1 = zc1[i]; break; }
  for (int i = 0; i < 8; ++i) if ((size_t)zc2[i] * slice2b <= avail) { z2 = zc2[i]; break; }
  const bool part1 = (z1 >= 4);
  const bool part2 = (z2 >= 4);
  void* P1 = P;                              // partial: z1 bf16 slices; atomic: f32
  void* P2 = P;                              // reused after reduce1 consumes P1

  build_g<<<NNODES, 256, 0, stream>>>(stru, mm, glw, w0, w1, G, EMB, W0T, W1T, RSUM);

  // S = G*G^T (1176 blocks, no rowsum) + X0T weight GEMM (96 tail blocks).
  gemm_sym_x0<<<1176 + 96, 256, 0, stream>>>(G, EMB, W0T, ADJ, X0T);

  // hop1: OUT1 = raw_adj @ X0 + fused ADJ rowsums. 64x256 tiles, K=6144 split.
  if (part1) {
    gemm_hop1<false><<<dim3(1, 96, z1), 256, 0, stream>>>(ADJ, X0T, P1, RSUM, NNODES, NNODES,
                                                          NNODES / z1, (size_t)NNODES * NHID);
    reduce1<true><<<NNODES / 2, 256, 0, stream>>>(P1, z1, RSUM, b0, H);
  } else {
    hipMemsetAsync(P1, 0, (size_t)NNODES * NHID * 4, stream);
    gemm_hop1<true><<<dim3(1, 96, 8), 256, 0, stream>>>(ADJ, X0T, P1, RSUM, NNODES, NNODES,
                                                        NNODES / 8, 0);
    reduce1<false><<<NNODES / 2, 256, 0, stream>>>(P1, 1, RSUM, b0, H);
  }

  // HW1T[j][node] = sum_d W1T[j][d]*H[node][d]
  gemm_nt<<<dim3(48, 1, 1), 256, 0, stream>>>(W1T, H, HW1T, NNODES, DIM, DIM, DIM);

  // hop2: OUT2 = raw_adj @ HW1. 128x128 tiles, K=6144 split.
  if (part2) {
    gemm_hop2<false><<<dim3(1, 48, z2), 256, 0, stream>>>(ADJ, HW1T, P2, NNODES, NNODES,
                                                          NNODES / z2, (size_t)NNODES * OFEAT);
    reduce2<true><<<NNODES / 4, 256, 0, stream>>>(P2, z2, RSUM, b1, out);
  } else {
    hipMemsetAsync(P2, 0, (size_t)NNODES * OFEAT * 4, stream);   // after P1 consumed
    gemm_hop2<true><<<dim3(1, 48, 16), 256, 0, stream>>>(ADJ, HW1T, P2, NNODES, NNODES,
                                                         NNODES / 16, 0);
    reduce2<false><<<NNODES / 4, 256, 0, stream>>>(P2, 1, RSUM, b1, out);
  }

  (void)in_sizes; (void)n_in; (void)out_size;
}

// Round 14
// 151.702 us; speedup vs baseline: 1.1306x; 1.1306x over previous
//
#include <hip/hip_runtime.h>
#include <stddef.h>

typedef unsigned short u16;
typedef float f32x4 __attribute__((ext_vector_type(4)));
typedef __bf16 bf16x8 __attribute__((ext_vector_type(8)));
typedef unsigned int u32;
typedef u32 u32x2 __attribute__((ext_vector_type(2)));

#define NNODES 6144
#define NUMS   3072
#define DIM    256
#define PPERS  4
#define KG     1024   /* P*DIM */
#define NHID   256
#define OFEAT  128

__device__ __forceinline__ u16 f2b(float f) {
  unsigned u = __float_as_uint(f);
  unsigned r = u + 0x7fffu + ((u >> 16) & 1u);   // RNE f32->bf16 (finite inputs)
  return (u16)(r >> 16);
}
__device__ __forceinline__ float b2f_lo(u32 v) { return __uint_as_float((v & 0xffffu) << 16); }
__device__ __forceinline__ float b2f_hi(u32 v) { return __uint_as_float((v >> 16) << 16); }

__device__ __forceinline__ void gload16(const void* g, void* l) {
  __builtin_amdgcn_global_load_lds((__attribute__((address_space(1))) void*)g,
                                   (__attribute__((address_space(3))) void*)l,
                                   16, 0, 0);
}

// ---------------------------------------------------------------------------
// Build G[n, p*256+d] = 0.5*(emb*glw_p)/||emb*glw_p||, EMB bf16 copy,
// + fused weight transposes (blocks < 256) and RSUM zeroing (blocks < 24).
// ---------------------------------------------------------------------------
__global__ void build_g(const float* __restrict__ stru, const float* __restrict__ mm,
                        const float* __restrict__ glw, const float* __restrict__ w0,
                        const float* __restrict__ w1, u16* __restrict__ G,
                        u16* __restrict__ EMB, u16* __restrict__ W0T,
                        u16* __restrict__ W1T, float* __restrict__ RSUM) {
  const int n = blockIdx.x;
  const int d = threadIdx.x;
  if (n < NHID)  W0T[n * DIM + d] = f2b(w0[(size_t)d * NHID + n]);
  if (n < OFEAT) W1T[n * DIM + d] = f2b(w1[(size_t)d * OFEAT + n]);
  if (n < 24)    RSUM[n * 256 + d] = 0.0f;

  const float* src = (n < NUMS) ? (stru + (size_t)n * DIM) : (mm + (size_t)(n - NUMS) * DIM);
  float e = src[d];
  EMB[(size_t)n * DIM + d] = f2b(e);
  __shared__ float red[16];
  float y[PPERS];
#pragma unroll
  for (int p = 0; p < PPERS; ++p) {
    y[p] = e * glw[p * DIM + d];
    float s = y[p] * y[p];
#pragma unroll
    for (int o = 32; o; o >>= 1) s += __shfl_xor(s, o);
    if ((d & 63) == 0) red[p * 4 + (d >> 6)] = s;
  }
  __syncthreads();
#pragma unroll
  for (int p = 0; p < PPERS; ++p) {
    float tot = red[p * 4 + 0] + red[p * 4 + 1] + red[p * 4 + 2] + red[p * 4 + 3];
    float inv = 0.5f / fmaxf(sqrtf(tot), 1e-12f);
    G[(size_t)n * KG + p * DIM + d] = f2b(y[p] * inv);
  }
}

// ---------------------------------------------------------------------------
// Merged kernel: blocks < 1176 -> symmetric Gram GEMM, NO rowsum (moved to
// hop1); blocks >= 1176 -> the 96-block X0T weight GEMM. Dual write of sym
// tiles (direct + LDS-transposed, 136-stride pad).
// ---------------------------------------------------------------------------
__global__ __launch_bounds__(256, 2)
void gemm_sym_x0(const u16* __restrict__ G, const u16* __restrict__ EMB,
                 const u16* __restrict__ W0T, u16* __restrict__ ADJ,
                 u16* __restrict__ X0T) {
  __shared__ __align__(16) u16 SMEM[128 * 136];
  u16* As = SMEM;
  u16* Bs = SMEM + 128 * 64;

  const int tid = threadIdx.x;
  const int lane = tid & 63;
  const int wv = tid >> 6;
  const int wr = wv >> 1, wc = wv & 1;
  const int lrow = lane & 15, kg = lane >> 4;

  f32x4 acc[4][4];
  const f32x4 zero = {0.f, 0.f, 0.f, 0.f};
#pragma unroll
  for (int i = 0; i < 4; ++i)
#pragma unroll
    for (int j = 0; j < 4; ++j) acc[i][j] = zero;

  if (blockIdx.x >= 1176) {
    // ---- X0T path: X0T[j][node] = sum_d W0T[j][d]*EMB[node][d], K=256 ----
    int u = blockIdx.x - 1176;
    const int m0 = (u / 48) * 128;
    const int n0 = (u % 48) * 128;
    for (int kt = 0; kt < DIM; kt += 64) {
      __syncthreads();
#pragma unroll
      for (int i = 0; i < 4; ++i) {
        int pos = i * 256 + wv * 64 + lane;
        int r = pos >> 3;
        int c = (pos & 7) * 8;
        int dstOff = (i * 256 + wv * 64) * 16;
        gload16(W0T + (size_t)(m0 + r) * DIM + kt + c, (char*)As + dstOff);
        gload16(EMB + (size_t)(n0 + r) * DIM + kt + c, (char*)Bs + dstOff);
      }
      __syncthreads();
#pragma unroll
      for (int kk = 0; kk < 2; ++kk) {
        bf16x8 a[4], b[4];
#pragma unroll
        for (int mi = 0; mi < 4; ++mi)
          a[mi] = *(const bf16x8*)&As[(wr * 64 + mi * 16 + lrow) * 64 + kk * 32 + kg * 8];
#pragma unroll
        for (int ni = 0; ni < 4; ++ni)
          b[ni] = *(const bf16x8*)&Bs[(wc * 64 + ni * 16 + lrow) * 64 + kk * 32 + kg * 8];
#pragma unroll
        for (int mi = 0; mi < 4; ++mi)
#pragma unroll
          for (int ni = 0; ni < 4; ++ni)
            acc[mi][ni] = __builtin_amdgcn_mfma_f32_16x16x32_bf16(a[mi], b[ni], acc[mi][ni], 0, 0, 0);
      }
    }
#pragma unroll
    for (int mi = 0; mi < 4; ++mi)
#pragma unroll
      for (int r = 0; r < 4; ++r) {
        int row = m0 + wr * 64 + mi * 16 + kg * 4 + r;
        size_t base = (size_t)row * NNODES;
#pragma unroll
        for (int ni = 0; ni < 4; ++ni) {
          int col = n0 + wc * 64 + ni * 16 + lrow;
          X0T[base + col] = f2b(acc[mi][ni][r]);
        }
      }
    return;
  }

  // ---- sym path ----
  int t = blockIdx.x;
  t = (t & 7) * 147 + (t >> 3);          // 1176 = 8 * 147, bijective XCD swizzle
  int rT = (int)((sqrtf(8.0f * (float)t + 1.0f) - 1.0f) * 0.5f);
  while ((rT + 1) * (rT + 2) / 2 <= t) ++rT;
  while (rT * (rT + 1) / 2 > t) --rT;
  const int cT = t - rT * (rT + 1) / 2;
  const int m0 = rT * 128;
  const int n0 = cT * 128;
  const bool diag = (rT == cT);

  for (int kt = 0; kt < KG; kt += 64) {
    __syncthreads();
#pragma unroll
    for (int i = 0; i < 4; ++i) {
      int pos = i * 256 + wv * 64 + lane;
      int r = pos >> 3;
      int c = (pos & 7) * 8;
      int dstOff = (i * 256 + wv * 64) * 16;
      gload16(G + (size_t)(m0 + r) * KG + kt + c, (char*)As + dstOff);
      gload16(G + (size_t)(n0 + r) * KG + kt + c, (char*)Bs + dstOff);
    }
    __syncthreads();
#pragma unroll
    for (int kk = 0; kk < 2; ++kk) {
      bf16x8 a[4], b[4];
#pragma unroll
      for (int mi = 0; mi < 4; ++mi)
        a[mi] = *(const bf16x8*)&As[(wr * 64 + mi * 16 + lrow) * 64 + kk * 32 + kg * 8];
#pragma unroll
      for (int ni = 0; ni < 4; ++ni)
        b[ni] = *(const bf16x8*)&Bs[(wc * 64 + ni * 16 + lrow) * 64 + kk * 32 + kg * 8];
#pragma unroll
      for (int mi = 0; mi < 4; ++mi)
#pragma unroll
        for (int ni = 0; ni < 4; ++ni)
          acc[mi][ni] = __builtin_amdgcn_mfma_f32_16x16x32_bf16(a[mi], b[ni], acc[mi][ni], 0, 0, 0);
    }
  }

  __syncthreads();   // K-loop fully done before SMEM reuse as T-buffer

  // relu in place
#pragma unroll
  for (int mi = 0; mi < 4; ++mi)
#pragma unroll
    for (int ni = 0; ni < 4; ++ni)
#pragma unroll
      for (int r = 0; r < 4; ++r) acc[mi][ni][r] = fmaxf(acc[mi][ni][r], 0.0f);

  // direct store + transpose pack (no rowsums here — hop1 computes them)
#pragma unroll
  for (int mi = 0; mi < 4; ++mi) {
#pragma unroll
    for (int r = 0; r < 4; ++r) {
      int row = m0 + wr * 64 + mi * 16 + kg * 4 + r;
      size_t base = (size_t)row * NNODES;
#pragma unroll
      for (int ni = 0; ni < 4; ++ni) {
        int col = n0 + wc * 64 + ni * 16 + lrow;
        ADJ[base + col] = f2b(acc[mi][ni][r]);
      }
    }
    if (!diag) {
#pragma unroll
      for (int ni = 0; ni < 4; ++ni) {
        int cl = wc * 64 + ni * 16 + lrow;
        int rl0 = wr * 64 + mi * 16 + kg * 4;
        u32x2 pack;
        pack[0] = (u32)f2b(acc[mi][ni][0]) | ((u32)f2b(acc[mi][ni][1]) << 16);
        pack[1] = (u32)f2b(acc[mi][ni][2]) | ((u32)f2b(acc[mi][ni][3]) << 16);
        *(u32x2*)&SMEM[cl * 136 + rl0] = pack;
      }
    }
  }

  if (!diag) {
    __syncthreads();
#pragma unroll
    for (int it = 0; it < 8; ++it) {
      int cid = it * 256 + tid;
      int rr = cid >> 4;
      int c8 = (cid & 15) * 8;
      bf16x8 v = *(const bf16x8*)&SMEM[rr * 136 + c8];
      *(bf16x8*)&ADJ[(size_t)(n0 + rr) * NNODES + m0 + c8] = v;
    }
  }
}

// ---------------------------------------------------------------------------
// NT bf16 GEMM 128x128 -> bf16 store (HW1T weight GEMM).
// ---------------------------------------------------------------------------
__global__ __launch_bounds__(256, 2)
void gemm_nt(const u16* __restrict__ A, const u16* __restrict__ B, u16* __restrict__ C,
             int N, int ldA, int ldB, int K) {
  __shared__ __align__(16) u16 As[128 * 64];
  __shared__ __align__(16) u16 Bs[128 * 64];
  const int tid = threadIdx.x;
  const int lane = tid & 63;
  const int wv = tid >> 6;
  const int m0 = blockIdx.y * 128;
  const int n0 = blockIdx.x * 128;
  const int wr = wv >> 1, wc = wv & 1;
  const int lrow = lane & 15, kg = lane >> 4;

  f32x4 acc[4][4];
  const f32x4 zero = {0.f, 0.f, 0.f, 0.f};
#pragma unroll
  for (int i = 0; i < 4; ++i)
#pragma unroll
    for (int j = 0; j < 4; ++j) acc[i][j] = zero;

  for (int kt = 0; kt < K; kt += 64) {
    __syncthreads();
#pragma unroll
    for (int i = 0; i < 4; ++i) {
      int pos = i * 256 + wv * 64 + lane;
      int r = pos >> 3;
      int c = (pos & 7) * 8;
      int dstOff = (i * 256 + wv * 64) * 16;
      gload16(A + (size_t)(m0 + r) * ldA + kt + c, (char*)As + dstOff);
      gload16(B + (size_t)(n0 + r) * ldB + kt + c, (char*)Bs + dstOff);
    }
    __syncthreads();
#pragma unroll
    for (int kk = 0; kk < 2; ++kk) {
      bf16x8 a[4], b[4];
#pragma unroll
      for (int mi = 0; mi < 4; ++mi)
        a[mi] = *(const bf16x8*)&As[(wr * 64 + mi * 16 + lrow) * 64 + kk * 32 + kg * 8];
#pragma unroll
      for (int ni = 0; ni < 4; ++ni)
        b[ni] = *(const bf16x8*)&Bs[(wc * 64 + ni * 16 + lrow) * 64 + kk * 32 + kg * 8];
#pragma unroll
      for (int mi = 0; mi < 4; ++mi)
#pragma unroll
        for (int ni = 0; ni < 4; ++ni)
          acc[mi][ni] = __builtin_amdgcn_mfma_f32_16x16x32_bf16(a[mi], b[ni], acc[mi][ni], 0, 0, 0);
    }
  }

#pragma unroll
  for (int mi = 0; mi < 4; ++mi)
#pragma unroll
    for (int r = 0; r < 4; ++r) {
      int row = m0 + wr * 64 + mi * 16 + kg * 4 + r;
      size_t base = (size_t)row * N;
#pragma unroll
      for (int ni = 0; ni < 4; ++ni) {
        int col = n0 + wc * 64 + ni * 16 + lrow;
        C[base + col] = f2b(acc[mi][ni][r]);
      }
    }
}

// ---------------------------------------------------------------------------
// hop1 GEMM: 64x256 tile, 4 waves in 1x4, BN=256 covers all of X0T.
// grid = (1, M/64, z). Partials: bf16 slices. Atomic fallback: f32.
// + FUSED ADJ ROWSUM: each block sums its staged As rows (its K-slice) and
// atomicAdds into RSUM (zeroed in build_g).
// ---------------------------------------------------------------------------
template <bool ATOMIC>
__global__ __launch_bounds__(256, 4)
void gemm_hop1(const u16* __restrict__ A, const u16* __restrict__ B, void* __restrict__ Cv,
               float* __restrict__ RSUM, int ldA, int ldB, int kPerSplit, size_t sliceElems) {
  __shared__ __align__(16) u16 As[64 * 64];     // 8 KB
  __shared__ __align__(16) u16 Bs[256 * 64];    // 32 KB
  const int tid = threadIdx.x;
  const int lane = tid & 63;
  const int wv = tid >> 6;
  const int m0 = blockIdx.y * 64;
  const int kBeg = blockIdx.z * kPerSplit;
  const int kEnd = kBeg + kPerSplit;
  const int lrow = lane & 15, kg = lane >> 4;

  f32x4 acc[4][4];
  const f32x4 zero = {0.f, 0.f, 0.f, 0.f};
#pragma unroll
  for (int i = 0; i < 4; ++i)
#pragma unroll
    for (int j = 0; j < 4; ++j) acc[i][j] = zero;

  float rs = 0.f;   // rowsum partial for row m0 + (tid>>2), quarter tid&3

  for (int kt = kBeg; kt < kEnd; kt += 64) {
    __syncthreads();
#pragma unroll
    for (int i = 0; i < 2; ++i) {   // A: 64 rows x 64 cols
      int pos = i * 256 + wv * 64 + lane;
      int r = pos >> 3;
      int c = (pos & 7) * 8;
      int dstOff = (i * 256 + wv * 64) * 16;
      gload16(A + (size_t)(m0 + r) * ldA + kt + c, (char*)As + dstOff);
    }
#pragma unroll
    for (int i = 0; i < 8; ++i) {   // B: 256 rows x 64 cols (global rows 0..255)
      int pos = i * 256 + wv * 64 + lane;
      int r = pos >> 3;
      int c = (pos & 7) * 8;
      int dstOff = (i * 256 + wv * 64) * 16;
      gload16(B + (size_t)r * ldB + kt + c, (char*)Bs + dstOff);
    }
    __syncthreads();
    // fused rowsum: thread sums 16 staged ADJ values of row tid>>2
    {
      const u32* rowp = (const u32*)&As[(tid >> 2) * 64 + (tid & 3) * 16];
      float s = 0.f;
#pragma unroll
      for (int j = 0; j < 8; ++j) { u32 v = rowp[j]; s += b2f_lo(v) + b2f_hi(v); }
      rs += s;
    }
#pragma unroll
    for (int kk = 0; kk < 2; ++kk) {
      bf16x8 a[4], b[4];
#pragma unroll
      for (int mi = 0; mi < 4; ++mi)
        a[mi] = *(const bf16x8*)&As[(mi * 16 + lrow) * 64 + kk * 32 + kg * 8];
#pragma unroll
      for (int ni = 0; ni < 4; ++ni)
        b[ni] = *(const bf16x8*)&Bs[(wv * 64 + ni * 16 + lrow) * 64 + kk * 32 + kg * 8];
#pragma unroll
      for (int mi = 0; mi < 4; ++mi)
#pragma unroll
        for (int ni = 0; ni < 4; ++ni)
          acc[mi][ni] = __builtin_amdgcn_mfma_f32_16x16x32_bf16(a[mi], b[ni], acc[mi][ni], 0, 0, 0);
    }
  }

  // rowsum: combine the 4 quarter-sums of each row (lanes differ in bits 0-1)
  rs += __shfl_xor(rs, 1);
  rs += __shfl_xor(rs, 2);
  if ((tid & 3) == 0) atomicAdd(&RSUM[m0 + (tid >> 2)], rs);

#pragma unroll
  for (int mi = 0; mi < 4; ++mi)
#pragma unroll
    for (int r = 0; r < 4; ++r) {
      int row = m0 + mi * 16 + kg * 4 + r;
      size_t base = (size_t)row * NHID;
#pragma unroll
      for (int ni = 0; ni < 4; ++ni) {
        int col = wv * 64 + ni * 16 + lrow;
        if (ATOMIC) atomicAdd(&((float*)Cv)[base + col], acc[mi][ni][r]);
        else ((u16*)Cv)[(size_t)blockIdx.z * sliceElems + base + col] = f2b(acc[mi][ni][r]);
      }
    }
}

// ---------------------------------------------------------------------------
// hop2 GEMM: 128x128 tile, split-K. grid = (1, M/128, z). N fixed = OFEAT.
// Partials: bf16 slices. Atomic fallback: f32.
// ---------------------------------------------------------------------------
template <bool ATOMIC>
__global__ __launch_bounds__(256, 4)
void gemm_hop2(const u16* __restrict__ A, const u16* __restrict__ B, void* __restrict__ Cv,
               int ldA, int ldB, int kPerSplit, size_t sliceElems) {
  __shared__ __align__(16) u16 As[128 * 64];
  __shared__ __align__(16) u16 Bs[128 * 64];
  const int tid = threadIdx.x;
  const int lane = tid & 63;
  const int wv = tid >> 6;
  const int m0 = blockIdx.y * 128;
  const int kBeg = blockIdx.z * kPerSplit;
  const int kEnd = kBeg + kPerSplit;
  const int wr = wv >> 1, wc = wv & 1;
  const int lrow = lane & 15, kg = lane >> 4;

  f32x4 acc[4][4];
  const f32x4 zero = {0.f, 0.f, 0.f, 0.f};
#pragma unroll
  for (int i = 0; i < 4; ++i)
#pragma unroll
    for (int j = 0; j < 4; ++j) acc[i][j] = zero;

  for (int kt = kBeg; kt < kEnd; kt += 64) {
    __syncthreads();
#pragma unroll
    for (int i = 0; i < 4; ++i) {
      int pos = i * 256 + wv * 64 + lane;
      int r = pos >> 3;
      int c = (pos & 7) * 8;
      int dstOff = (i * 256 + wv * 64) * 16;
      gload16(A + (size_t)(m0 + r) * ldA + kt + c, (char*)As + dstOff);
      gload16(B + (size_t)r * ldB + kt + c, (char*)Bs + dstOff);   // B rows 0..127
    }
    __syncthreads();
#pragma unroll
    for (int kk = 0; kk < 2; ++kk) {
      bf16x8 a[4], b[4];
#pragma unroll
      for (int mi = 0; mi < 4; ++mi)
        a[mi] = *(const bf16x8*)&As[(wr * 64 + mi * 16 + lrow) * 64 + kk * 32 + kg * 8];
#pragma unroll
      for (int ni = 0; ni < 4; ++ni)
        b[ni] = *(const bf16x8*)&Bs[(wc * 64 + ni * 16 + lrow) * 64 + kk * 32 + kg * 8];
#pragma unroll
      for (int mi = 0; mi < 4; ++mi)
#pragma unroll
        for (int ni = 0; ni < 4; ++ni)
          acc[mi][ni] = __builtin_amdgcn_mfma_f32_16x16x32_bf16(a[mi], b[ni], acc[mi][ni], 0, 0, 0);
    }
  }

#pragma unroll
  for (int mi = 0; mi < 4; ++mi)
#pragma unroll
    for (int r = 0; r < 4; ++r) {
      int row = m0 + wr * 64 + mi * 16 + kg * 4 + r;
      size_t base = (size_t)row * OFEAT;
#pragma unroll
      for (int ni = 0; ni < 4; ++ni) {
        int col = wc * 64 + ni * 16 + lrow;
        if (ATOMIC) atomicAdd(&((float*)Cv)[base + col], acc[mi][ni][r]);
        else ((u16*)Cv)[(size_t)blockIdx.z * sliceElems + base + col] = f2b(acc[mi][ni][r]);
      }
    }
}

// reduce1: H[n][j] = bf16(relu( (sum_s P1[s][n][j]) / rowsum[n] + b0[j] ))
template <bool BF16P>
__global__ void reduce1(const void* __restrict__ P1v, int z, const float* __restrict__ RSUM,
                        const float* __restrict__ b0, u16* __restrict__ H) {
  const int tid = threadIdx.x;
  const int n = blockIdx.x * 2 + (tid >> 7);
  const int j0 = (tid & 127) * 2;
  float s0 = 0.f, s1 = 0.f;
  if (BF16P) {
    const u16* P = (const u16*)P1v;
    for (int s = 0; s < z; ++s) {
      u32 v = *(const u32*)&P[((size_t)s * NNODES + n) * NHID + j0];
      s0 += b2f_lo(v); s1 += b2f_hi(v);
    }
  } else {
    const float* P = (const float*)P1v;
    s0 = P[(size_t)n * NHID + j0];
    s1 = P[(size_t)n * NHID + j0 + 1];
  }
  float inv = 1.0f / fmaxf(RSUM[n], 1e-12f);
  float h0 = fmaxf(s0 * inv + b0[j0], 0.f);
  float h1 = fmaxf(s1 * inv + b0[j0 + 1], 0.f);
  *(u32*)&H[(size_t)n * NHID + j0] = (u32)f2b(h0) | ((u32)f2b(h1) << 16);
}

// reduce2: out[n][j] = log_softmax_j( (sum_s P2[s][n][j]) / rowsum[n] + b1[j] )
template <bool BF16P>
__global__ void reduce2(const void* __restrict__ P2v, int z, const float* __restrict__ RSUM,
                        const float* __restrict__ b1, float* __restrict__ out) {
  const int tid = threadIdx.x;
  const int n = blockIdx.x * 4 + (tid >> 6);
  const int j0 = (tid & 63) * 2;
  float s0 = 0.f, s1 = 0.f;
  if (BF16P) {
    const u16* P = (const u16*)P2v;
    for (int s = 0; s < z; ++s) {
      u32 v = *(const u32*)&P[((size_t)s * NNODES + n) * OFEAT + j0];
      s0 += b2f_lo(v); s1 += b2f_hi(v);
    }
  } else {
    const float* P = (const float*)P2v;
    s0 = P[(size_t)n * OFEAT + j0];
    s1 = P[(size_t)n * OFEAT + j0 + 1];
  }
  float inv = 1.0f / fmaxf(RSUM[n], 1e-12f);
  float x0 = s0 * inv + b1[j0];
  float x1 = s1 * inv + b1[j0 + 1];
  float m = fmaxf(x0, x1);
#pragma unroll
  for (int o = 32; o; o >>= 1) m = fmaxf(m, __shfl_xor(m, o));
  float e = expf(x0 - m) + expf(x1 - m);
#pragma unroll
  for (int o = 32; o; o >>= 1) e += __shfl_xor(e, o);
  float lse = m + logf(e);
  out[(size_t)n * OFEAT + j0]     = x0 - lse;
  out[(size_t)n * OFEAT + j0 + 1] = x1 - lse;
}

extern "C" void kernel_launch(void* const* d_in, const int* in_sizes, int n_in,
                              void* d_out, int out_size, void* d_ws, size_t ws_size,
                              hipStream_t stream) {
  const float* stru = (const float*)d_in[0];
  const float* mm   = (const float*)d_in[1];
  const float* glw  = (const float*)d_in[2];
  const float* w0   = (const float*)d_in[3];
  const float* b0   = (const float*)d_in[4];
  const float* w1   = (const float*)d_in[5];
  const float* b1   = (const float*)d_in[6];
  float* out = (float*)d_out;

  char* ws = (char*)d_ws;
  size_t off = 0;
  auto carve = [&](size_t bytes) -> void* {
    void* p = ws + off;
    off += (bytes + 255) & ~(size_t)255;
    return p;
  };
  u16*   G     = (u16*)carve((size_t)NNODES * KG * 2);        // 12.6 MB
  u16*   EMB   = (u16*)carve((size_t)NNODES * DIM * 2);       // 3.1 MB
  u16*   W0T   = (u16*)carve((size_t)NHID * DIM * 2);
  u16*   W1T   = (u16*)carve((size_t)OFEAT * DIM * 2);
  u16*   ADJ   = (u16*)carve((size_t)NNODES * NNODES * 2);    // 75.5 MB
  u16*   X0T   = (u16*)carve((size_t)NHID * NNODES * 2);      // 3.1 MB
  u16*   H     = (u16*)carve((size_t)NNODES * NHID * 2);      // 3.1 MB
  u16*   HW1T  = (u16*)carve((size_t)OFEAT * NNODES * 2);     // 1.6 MB
  float* RSUM  = (float*)carve((size_t)NNODES * 4);           // 24 KB

  // remaining workspace -> bf16 split-K partial slices
  const size_t slice1b = (size_t)NNODES * NHID * 2;   // 3.15 MB (bf16)
  const size_t slice2b = (size_t)NNODES * OFEAT * 2;  // 1.57 MB (bf16)
  size_t avail = (ws_size > off) ? (ws_size - off) : 0;
  char* P = ws + off;

  const int zc1[6] = {8, 6, 4, 3, 2, 1};
  const int zc2[8] = {16, 12, 8, 6, 4, 3, 2, 1};
  int z1 = 1, z2 = 1;
  for (int i = 0; i < 6; ++i) if ((size_t)zc1[i] * slice1b <= avail) { z1 = zc1[i]; break; }
  for (int i = 0; i < 8; ++i) if ((size_t)zc2[i] * slice2b <= avail) { z2 = zc2[i]; break; }
  const bool part1 = (z1 >= 4);
  const bool part2 = (z2 >= 4);
  void* P1 = P;                              // partial: z1 bf16 slices; atomic: f32
  void* P2 = P;                              // reused after reduce1 consumes P1

  build_g<<<NNODES, 256, 0, stream>>>(stru, mm, glw, w0, w1, G, EMB, W0T, W1T, RSUM);

  // S = G*G^T (1176 blocks, no rowsum) + X0T weight GEMM (96 tail blocks).
  gemm_sym_x0<<<1176 + 96, 256, 0, stream>>>(G, EMB, W0T, ADJ, X0T);

  // hop1: OUT1 = raw_adj @ X0 + fused ADJ rowsums. 64x256 tiles, K=6144 split.
  if (part1) {
    gemm_hop1<false><<<dim3(1, 96, z1), 256, 0, stream>>>(ADJ, X0T, P1, RSUM, NNODES, NNODES,
                                                          NNODES / z1, (size_t)NNODES * NHID);
    reduce1<true><<<NNODES / 2, 256, 0, stream>>>(P1, z1, RSUM, b0, H);
  } else {
    hipMemsetAsync(P1, 0, (size_t)NNODES * NHID * 4, stream);
    gemm_hop1<true><<<dim3(1, 96, 8), 256, 0, stream>>>(ADJ, X0T, P1, RSUM, NNODES, NNODES,
                                                        NNODES / 8, 0);
    reduce1<false><<<NNODES / 2, 256, 0, stream>>>(P1, 1, RSUM, b0, H);
  }

  // HW1T[j][node] = sum_d W1T[j][d]*H[node][d]
  gemm_nt<<<dim3(48, 1, 1), 256, 0, stream>>>(W1T, H, HW1T, NNODES, DIM, DIM, DIM);

  // hop2: OUT2 = raw_adj @ HW1. 128x128 tiles, K=6144 split.
  if (part2) {
    gemm_hop2<false><<<dim3(1, 48, z2), 256, 0, stream>>>(ADJ, HW1T, P2, NNODES, NNODES,
                                                          NNODES / z2, (size_t)NNODES * OFEAT);
    reduce2<true><<<NNODES / 4, 256, 0, stream>>>(P2, z2, RSUM, b1, out);
  } else {
    hipMemsetAsync(P2, 0, (size_t)NNODES * OFEAT * 4, stream);   // after P1 consumed
    gemm_hop2<true><<<dim3(1, 48, 16), 256, 0, stream>>>(ADJ, HW1T, P2, NNODES, NNODES,
                                                         NNODES / 16, 0);
    reduce2<false><<<NNODES / 4, 256, 0, stream>>>(P2, 1, RSUM, b1, out);
  }

  (void)in_sizes; (void)n_in; (void)out_size;
}

// Round 15
// 151.639 us; speedup vs baseline: 1.1311x; 1.0004x over previous
//
#include <hip/hip_runtime.h>
#include <stddef.h>

typedef unsigned short u16;
typedef float f32x4 __attribute__((ext_vector_type(4)));
typedef __bf16 bf16x8 __attribute__((ext_vector_type(8)));
typedef unsigned int u32;
typedef u32 u32x2 __attribute__((ext_vector_type(2)));

#define NNODES 6144
#define NUMS   3072
#define DIM    256
#define PPERS  4
#define KG     1024   /* P*DIM */
#define NHID   256
#define OFEAT  128

__device__ __forceinline__ u16 f2b(float f) {
  unsigned u = __float_as_uint(f);
  unsigned r = u + 0x7fffu + ((u >> 16) & 1u);   // RNE f32->bf16 (finite inputs)
  return (u16)(r >> 16);
}
__device__ __forceinline__ float b2f_lo(u32 v) { return __uint_as_float((v & 0xffffu) << 16); }
__device__ __forceinline__ float b2f_hi(u32 v) { return __uint_as_float((v >> 16) << 16); }

__device__ __forceinline__ void gload16(const void* g, void* l) {
  __builtin_amdgcn_global_load_lds((__attribute__((address_space(1))) void*)g,
                                   (__attribute__((address_space(3))) void*)l,
                                   16, 0, 0);
}

// ---------------------------------------------------------------------------
// Build G[n, p*256+d] = 0.5*(emb*glw_p)/||emb*glw_p||, EMB bf16 copy,
// + fused weight transposes (blocks < 256) and RSUM zeroing (blocks < 24).
// ---------------------------------------------------------------------------
__global__ void build_g(const float* __restrict__ stru, const float* __restrict__ mm,
                        const float* __restrict__ glw, const float* __restrict__ w0,
                        const float* __restrict__ w1, u16* __restrict__ G,
                        u16* __restrict__ EMB, u16* __restrict__ W0T,
                        u16* __restrict__ W1T, float* __restrict__ RSUM) {
  const int n = blockIdx.x;
  const int d = threadIdx.x;
  if (n < NHID)  W0T[n * DIM + d] = f2b(w0[(size_t)d * NHID + n]);
  if (n < OFEAT) W1T[n * DIM + d] = f2b(w1[(size_t)d * OFEAT + n]);
  if (n < 24)    RSUM[n * 256 + d] = 0.0f;

  const float* src = (n < NUMS) ? (stru + (size_t)n * DIM) : (mm + (size_t)(n - NUMS) * DIM);
  float e = src[d];
  EMB[(size_t)n * DIM + d] = f2b(e);
  __shared__ float red[16];
  float y[PPERS];
#pragma unroll
  for (int p = 0; p < PPERS; ++p) {
    y[p] = e * glw[p * DIM + d];
    float s = y[p] * y[p];
#pragma unroll
    for (int o = 32; o; o >>= 1) s += __shfl_xor(s, o);
    if ((d & 63) == 0) red[p * 4 + (d >> 6)] = s;
  }
  __syncthreads();
#pragma unroll
  for (int p = 0; p < PPERS; ++p) {
    float tot = red[p * 4 + 0] + red[p * 4 + 1] + red[p * 4 + 2] + red[p * 4 + 3];
    float inv = 0.5f / fmaxf(sqrtf(tot), 1e-12f);
    G[(size_t)n * KG + p * DIM + d] = f2b(y[p] * inv);
  }
}

// ---------------------------------------------------------------------------
// Merged kernel: blocks < 1176 -> symmetric Gram GEMM, NO rowsum (moved to
// hop1); blocks >= 1176 -> the 96-block X0T weight GEMM. Dual write of sym
// tiles (direct + LDS-transposed, 136-stride pad).
// ---------------------------------------------------------------------------
__global__ __launch_bounds__(256, 2)
void gemm_sym_x0(const u16* __restrict__ G, const u16* __restrict__ EMB,
                 const u16* __restrict__ W0T, u16* __restrict__ ADJ,
                 u16* __restrict__ X0T) {
  __shared__ __align__(16) u16 SMEM[128 * 136];
  u16* As = SMEM;
  u16* Bs = SMEM + 128 * 64;

  const int tid = threadIdx.x;
  const int lane = tid & 63;
  const int wv = tid >> 6;
  const int wr = wv >> 1, wc = wv & 1;
  const int lrow = lane & 15, kg = lane >> 4;

  f32x4 acc[4][4];
  const f32x4 zero = {0.f, 0.f, 0.f, 0.f};
#pragma unroll
  for (int i = 0; i < 4; ++i)
#pragma unroll
    for (int j = 0; j < 4; ++j) acc[i][j] = zero;

  if (blockIdx.x >= 1176) {
    // ---- X0T path: X0T[j][node] = sum_d W0T[j][d]*EMB[node][d], K=256 ----
    int u = blockIdx.x - 1176;
    const int m0 = (u / 48) * 128;
    const int n0 = (u % 48) * 128;
    for (int kt = 0; kt < DIM; kt += 64) {
      __syncthreads();
#pragma unroll
      for (int i = 0; i < 4; ++i) {
        int pos = i * 256 + wv * 64 + lane;
        int r = pos >> 3;
        int c = (pos & 7) * 8;
        int dstOff = (i * 256 + wv * 64) * 16;
        gload16(W0T + (size_t)(m0 + r) * DIM + kt + c, (char*)As + dstOff);
        gload16(EMB + (size_t)(n0 + r) * DIM + kt + c, (char*)Bs + dstOff);
      }
      __syncthreads();
#pragma unroll
      for (int kk = 0; kk < 2; ++kk) {
        bf16x8 a[4], b[4];
#pragma unroll
        for (int mi = 0; mi < 4; ++mi)
          a[mi] = *(const bf16x8*)&As[(wr * 64 + mi * 16 + lrow) * 64 + kk * 32 + kg * 8];
#pragma unroll
        for (int ni = 0; ni < 4; ++ni)
          b[ni] = *(const bf16x8*)&Bs[(wc * 64 + ni * 16 + lrow) * 64 + kk * 32 + kg * 8];
#pragma unroll
        for (int mi = 0; mi < 4; ++mi)
#pragma unroll
          for (int ni = 0; ni < 4; ++ni)
            acc[mi][ni] = __builtin_amdgcn_mfma_f32_16x16x32_bf16(a[mi], b[ni], acc[mi][ni], 0, 0, 0);
      }
    }
#pragma unroll
    for (int mi = 0; mi < 4; ++mi)
#pragma unroll
      for (int r = 0; r < 4; ++r) {
        int row = m0 + wr * 64 + mi * 16 + kg * 4 + r;
        size_t base = (size_t)row * NNODES;
#pragma unroll
        for (int ni = 0; ni < 4; ++ni) {
          int col = n0 + wc * 64 + ni * 16 + lrow;
          X0T[base + col] = f2b(acc[mi][ni][r]);
        }
      }
    return;
  }

  // ---- sym path ----
  int t = blockIdx.x;
  t = (t & 7) * 147 + (t >> 3);          // 1176 = 8 * 147, bijective XCD swizzle
  int rT = (int)((sqrtf(8.0f * (float)t + 1.0f) - 1.0f) * 0.5f);
  while ((rT + 1) * (rT + 2) / 2 <= t) ++rT;
  while (rT * (rT + 1) / 2 > t) --rT;
  const int cT = t - rT * (rT + 1) / 2;
  const int m0 = rT * 128;
  const int n0 = cT * 128;
  const bool diag = (rT == cT);

  for (int kt = 0; kt < KG; kt += 64) {
    __syncthreads();
#pragma unroll
    for (int i = 0; i < 4; ++i) {
      int pos = i * 256 + wv * 64 + lane;
      int r = pos >> 3;
      int c = (pos & 7) * 8;
      int dstOff = (i * 256 + wv * 64) * 16;
      gload16(G + (size_t)(m0 + r) * KG + kt + c, (char*)As + dstOff);
      gload16(G + (size_t)(n0 + r) * KG + kt + c, (char*)Bs + dstOff);
    }
    __syncthreads();
#pragma unroll
    for (int kk = 0; kk < 2; ++kk) {
      bf16x8 a[4], b[4];
#pragma unroll
      for (int mi = 0; mi < 4; ++mi)
        a[mi] = *(const bf16x8*)&As[(wr * 64 + mi * 16 + lrow) * 64 + kk * 32 + kg * 8];
#pragma unroll
      for (int ni = 0; ni < 4; ++ni)
        b[ni] = *(const bf16x8*)&Bs[(wc * 64 + ni * 16 + lrow) * 64 + kk * 32 + kg * 8];
#pragma unroll
      for (int mi = 0; mi < 4; ++mi)
#pragma unroll
        for (int ni = 0; ni < 4; ++ni)
          acc[mi][ni] = __builtin_amdgcn_mfma_f32_16x16x32_bf16(a[mi], b[ni], acc[mi][ni], 0, 0, 0);
    }
  }

  __syncthreads();   // K-loop fully done before SMEM reuse as T-buffer

  // relu in place
#pragma unroll
  for (int mi = 0; mi < 4; ++mi)
#pragma unroll
    for (int ni = 0; ni < 4; ++ni)
#pragma unroll
      for (int r = 0; r < 4; ++r) acc[mi][ni][r] = fmaxf(acc[mi][ni][r], 0.0f);

  // direct store + transpose pack (no rowsums here — hop1 computes them)
#pragma unroll
  for (int mi = 0; mi < 4; ++mi) {
#pragma unroll
    for (int r = 0; r < 4; ++r) {
      int row = m0 + wr * 64 + mi * 16 + kg * 4 + r;
      size_t base = (size_t)row * NNODES;
#pragma unroll
      for (int ni = 0; ni < 4; ++ni) {
        int col = n0 + wc * 64 + ni * 16 + lrow;
        ADJ[base + col] = f2b(acc[mi][ni][r]);
      }
    }
    if (!diag) {
#pragma unroll
      for (int ni = 0; ni < 4; ++ni) {
        int cl = wc * 64 + ni * 16 + lrow;
        int rl0 = wr * 64 + mi * 16 + kg * 4;
        u32x2 pack;
        pack[0] = (u32)f2b(acc[mi][ni][0]) | ((u32)f2b(acc[mi][ni][1]) << 16);
        pack[1] = (u32)f2b(acc[mi][ni][2]) | ((u32)f2b(acc[mi][ni][3]) << 16);
        *(u32x2*)&SMEM[cl * 136 + rl0] = pack;
      }
    }
  }

  if (!diag) {
    __syncthreads();
#pragma unroll
    for (int it = 0; it < 8; ++it) {
      int cid = it * 256 + tid;
      int rr = cid >> 4;
      int c8 = (cid & 15) * 8;
      bf16x8 v = *(const bf16x8*)&SMEM[rr * 136 + c8];
      *(bf16x8*)&ADJ[(size_t)(n0 + rr) * NNODES + m0 + c8] = v;
    }
  }
}

// ---------------------------------------------------------------------------
// NT bf16 GEMM 128x128 -> bf16 store (HW1T weight GEMM).
// ---------------------------------------------------------------------------
__global__ __launch_bounds__(256, 2)
void gemm_nt(const u16* __restrict__ A, const u16* __restrict__ B, u16* __restrict__ C,
             int N, int ldA, int ldB, int K) {
  __shared__ __align__(16) u16 As[128 * 64];
  __shared__ __align__(16) u16 Bs[128 * 64];
  const int tid = threadIdx.x;
  const int lane = tid & 63;
  const int wv = tid >> 6;
  const int m0 = blockIdx.y * 128;
  const int n0 = blockIdx.x * 128;
  const int wr = wv >> 1, wc = wv & 1;
  const int lrow = lane & 15, kg = lane >> 4;

  f32x4 acc[4][4];
  const f32x4 zero = {0.f, 0.f, 0.f, 0.f};
#pragma unroll
  for (int i = 0; i < 4; ++i)
#pragma unroll
    for (int j = 0; j < 4; ++j) acc[i][j] = zero;

  for (int kt = 0; kt < K; kt += 64) {
    __syncthreads();
#pragma unroll
    for (int i = 0; i < 4; ++i) {
      int pos = i * 256 + wv * 64 + lane;
      int r = pos >> 3;
      int c = (pos & 7) * 8;
      int dstOff = (i * 256 + wv * 64) * 16;
      gload16(A + (size_t)(m0 + r) * ldA + kt + c, (char*)As + dstOff);
      gload16(B + (size_t)(n0 + r) * ldB + kt + c, (char*)Bs + dstOff);
    }
    __syncthreads();
#pragma unroll
    for (int kk = 0; kk < 2; ++kk) {
      bf16x8 a[4], b[4];
#pragma unroll
      for (int mi = 0; mi < 4; ++mi)
        a[mi] = *(const bf16x8*)&As[(wr * 64 + mi * 16 + lrow) * 64 + kk * 32 + kg * 8];
#pragma unroll
      for (int ni = 0; ni < 4; ++ni)
        b[ni] = *(const bf16x8*)&Bs[(wc * 64 + ni * 16 + lrow) * 64 + kk * 32 + kg * 8];
#pragma unroll
      for (int mi = 0; mi < 4; ++mi)
#pragma unroll
        for (int ni = 0; ni < 4; ++ni)
          acc[mi][ni] = __builtin_amdgcn_mfma_f32_16x16x32_bf16(a[mi], b[ni], acc[mi][ni], 0, 0, 0);
    }
  }

#pragma unroll
  for (int mi = 0; mi < 4; ++mi)
#pragma unroll
    for (int r = 0; r < 4; ++r) {
      int row = m0 + wr * 64 + mi * 16 + kg * 4 + r;
      size_t base = (size_t)row * N;
#pragma unroll
      for (int ni = 0; ni < 4; ++ni) {
        int col = n0 + wc * 64 + ni * 16 + lrow;
        C[base + col] = f2b(acc[mi][ni][r]);
      }
    }
}

// ---------------------------------------------------------------------------
// hop1 GEMM: 64x256 tile, 4 waves in 1x4, BN=256 covers all of X0T.
// grid = (1, M/64, z). Partials: bf16 slices. Atomic fallback: f32.
// + FUSED ADJ ROWSUM: each block sums its staged As rows (its K-slice) and
// atomicAdds into RSUM (zeroed in build_g).
// ---------------------------------------------------------------------------
template <bool ATOMIC>
__global__ __launch_bounds__(256, 4)
void gemm_hop1(const u16* __restrict__ A, const u16* __restrict__ B, void* __restrict__ Cv,
               float* __restrict__ RSUM, int ldA, int ldB, int kPerSplit, size_t sliceElems) {
  __shared__ __align__(16) u16 As[64 * 64];     // 8 KB
  __shared__ __align__(16) u16 Bs[256 * 64];    // 32 KB
  const int tid = threadIdx.x;
  const int lane = tid & 63;
  const int wv = tid >> 6;
  const int m0 = blockIdx.y * 64;
  const int kBeg = blockIdx.z * kPerSplit;
  const int kEnd = kBeg + kPerSplit;
  const int lrow = lane & 15, kg = lane >> 4;

  f32x4 acc[4][4];
  const f32x4 zero = {0.f, 0.f, 0.f, 0.f};
#pragma unroll
  for (int i = 0; i < 4; ++i)
#pragma unroll
    for (int j = 0; j < 4; ++j) acc[i][j] = zero;

  float rs = 0.f;   // rowsum partial for row m0 + (tid>>2), quarter tid&3

  for (int kt = kBeg; kt < kEnd; kt += 64) {
    __syncthreads();
#pragma unroll
    for (int i = 0; i < 2; ++i) {   // A: 64 rows x 64 cols
      int pos = i * 256 + wv * 64 + lane;
      int r = pos >> 3;
      int c = (pos & 7) * 8;
      int dstOff = (i * 256 + wv * 64) * 16;
      gload16(A + (size_t)(m0 + r) * ldA + kt + c, (char*)As + dstOff);
    }
#pragma unroll
    for (int i = 0; i < 8; ++i) {   // B: 256 rows x 64 cols (global rows 0..255)
      int pos = i * 256 + wv * 64 + lane;
      int r = pos >> 3;
      int c = (pos & 7) * 8;
      int dstOff = (i * 256 + wv * 64) * 16;
      gload16(B + (size_t)r * ldB + kt + c, (char*)Bs + dstOff);
    }
    __syncthreads();
    // fused rowsum: thread sums 16 staged ADJ values of row tid>>2
    {
      const u32* rowp = (const u32*)&As[(tid >> 2) * 64 + (tid & 3) * 16];
      float s = 0.f;
#pragma unroll
      for (int j = 0; j < 8; ++j) { u32 v = rowp[j]; s += b2f_lo(v) + b2f_hi(v); }
      rs += s;
    }
#pragma unroll
    for (int kk = 0; kk < 2; ++kk) {
      bf16x8 a[4], b[4];
#pragma unroll
      for (int mi = 0; mi < 4; ++mi)
        a[mi] = *(const bf16x8*)&As[(mi * 16 + lrow) * 64 + kk * 32 + kg * 8];
#pragma unroll
      for (int ni = 0; ni < 4; ++ni)
        b[ni] = *(const bf16x8*)&Bs[(wv * 64 + ni * 16 + lrow) * 64 + kk * 32 + kg * 8];
#pragma unroll
      for (int mi = 0; mi < 4; ++mi)
#pragma unroll
        for (int ni = 0; ni < 4; ++ni)
          acc[mi][ni] = __builtin_amdgcn_mfma_f32_16x16x32_bf16(a[mi], b[ni], acc[mi][ni], 0, 0, 0);
    }
  }

  // rowsum: combine the 4 quarter-sums of each row (lanes differ in bits 0-1)
  rs += __shfl_xor(rs, 1);
  rs += __shfl_xor(rs, 2);
  if ((tid & 3) == 0) atomicAdd(&RSUM[m0 + (tid >> 2)], rs);

#pragma unroll
  for (int mi = 0; mi < 4; ++mi)
#pragma unroll
    for (int r = 0; r < 4; ++r) {
      int row = m0 + mi * 16 + kg * 4 + r;
      size_t base = (size_t)row * NHID;
#pragma unroll
      for (int ni = 0; ni < 4; ++ni) {
        int col = wv * 64 + ni * 16 + lrow;
        if (ATOMIC) atomicAdd(&((float*)Cv)[base + col], acc[mi][ni][r]);
        else ((u16*)Cv)[(size_t)blockIdx.z * sliceElems + base + col] = f2b(acc[mi][ni][r]);
      }
    }
}

// ---------------------------------------------------------------------------
// hop2 GEMM: 128x128 tile, split-K. grid = (1, M/128, z). N fixed = OFEAT.
// Partials: bf16 slices. Atomic fallback: f32.
// ---------------------------------------------------------------------------
template <bool ATOMIC>
__global__ __launch_bounds__(256, 4)
void gemm_hop2(const u16* __restrict__ A, const u16* __restrict__ B, void* __restrict__ Cv,
               int ldA, int ldB, int kPerSplit, size_t sliceElems) {
  __shared__ __align__(16) u16 As[128 * 64];
  __shared__ __align__(16) u16 Bs[128 * 64];
  const int tid = threadIdx.x;
  const int lane = tid & 63;
  const int wv = tid >> 6;
  const int m0 = blockIdx.y * 128;
  const int kBeg = blockIdx.z * kPerSplit;
  const int kEnd = kBeg + kPerSplit;
  const int wr = wv >> 1, wc = wv & 1;
  const int lrow = lane & 15, kg = lane >> 4;

  f32x4 acc[4][4];
  const f32x4 zero = {0.f, 0.f, 0.f, 0.f};
#pragma unroll
  for (int i = 0; i < 4; ++i)
#pragma unroll
    for (int j = 0; j < 4; ++j) acc[i][j] = zero;

  for (int kt = kBeg; kt < kEnd; kt += 64) {
    __syncthreads();
#pragma unroll
    for (int i = 0; i < 4; ++i) {
      int pos = i * 256 + wv * 64 + lane;
      int r = pos >> 3;
      int c = (pos & 7) * 8;
      int dstOff = (i * 256 + wv * 64) * 16;
      gload16(A + (size_t)(m0 + r) * ldA + kt + c, (char*)As + dstOff);
      gload16(B + (size_t)r * ldB + kt + c, (char*)Bs + dstOff);   // B rows 0..127
    }
    __syncthreads();
#pragma unroll
    for (int kk = 0; kk < 2; ++kk) {
      bf16x8 a[4], b[4];
#pragma unroll
      for (int mi = 0; mi < 4; ++mi)
        a[mi] = *(const bf16x8*)&As[(wr * 64 + mi * 16 + lrow) * 64 + kk * 32 + kg * 8];
#pragma unroll
      for (int ni = 0; ni < 4; ++ni)
        b[ni] = *(const bf16x8*)&Bs[(wc * 64 + ni * 16 + lrow) * 64 + kk * 32 + kg * 8];
#pragma unroll
      for (int mi = 0; mi < 4; ++mi)
#pragma unroll
        for (int ni = 0; ni < 4; ++ni)
          acc[mi][ni] = __builtin_amdgcn_mfma_f32_16x16x32_bf16(a[mi], b[ni], acc[mi][ni], 0, 0, 0);
    }
  }

#pragma unroll
  for (int mi = 0; mi < 4; ++mi)
#pragma unroll
    for (int r = 0; r < 4; ++r) {
      int row = m0 + wr * 64 + mi * 16 + kg * 4 + r;
      size_t base = (size_t)row * OFEAT;
#pragma unroll
      for (int ni = 0; ni < 4; ++ni) {
        int col = wc * 64 + ni * 16 + lrow;
        if (ATOMIC) atomicAdd(&((float*)Cv)[base + col], acc[mi][ni][r]);
        else ((u16*)Cv)[(size_t)blockIdx.z * sliceElems + base + col] = f2b(acc[mi][ni][r]);
      }
    }
}

// reduce1: H[n][j] = bf16(relu( (sum_s P1[s][n][j]) / rowsum[n] + b0[j] ))
template <bool BF16P>
__global__ void reduce1(const void* __restrict__ P1v, int z, const float* __restrict__ RSUM,
                        const float* __restrict__ b0, u16* __restrict__ H) {
  const int tid = threadIdx.x;
  const int n = blockIdx.x * 2 + (tid >> 7);
  const int j0 = (tid & 127) * 2;
  float s0 = 0.f, s1 = 0.f;
  if (BF16P) {
    const u16* P = (const u16*)P1v;
    for (int s = 0; s < z; ++s) {
      u32 v = *(const u32*)&P[((size_t)s * NNODES + n) * NHID + j0];
      s0 += b2f_lo(v); s1 += b2f_hi(v);
    }
  } else {
    const float* P = (const float*)P1v;
    s0 = P[(size_t)n * NHID + j0];
    s1 = P[(size_t)n * NHID + j0 + 1];
  }
  float inv = 1.0f / fmaxf(RSUM[n], 1e-12f);
  float h0 = fmaxf(s0 * inv + b0[j0], 0.f);
  float h1 = fmaxf(s1 * inv + b0[j0 + 1], 0.f);
  *(u32*)&H[(size_t)n * NHID + j0] = (u32)f2b(h0) | ((u32)f2b(h1) << 16);
}

// reduce2: out[n][j] = log_softmax_j( (sum_s P2[s][n][j]) / rowsum[n] + b1[j] )
template <bool BF16P>
__global__ void reduce2(const void* __restrict__ P2v, int z, const float* __restrict__ RSUM,
                        const float* __restrict__ b1, float* __restrict__ out) {
  const int tid = threadIdx.x;
  const int n = blockIdx.x * 4 + (tid >> 6);
  const int j0 = (tid & 63) * 2;
  float s0 = 0.f, s1 = 0.f;
  if (BF16P) {
    const u16* P = (const u16*)P2v;
    for (int s = 0; s < z; ++s) {
      u32 v = *(const u32*)&P[((size_t)s * NNODES + n) * OFEAT + j0];
      s0 += b2f_lo(v); s1 += b2f_hi(v);
    }
  } else {
    const float* P = (const float*)P2v;
    s0 = P[(size_t)n * OFEAT + j0];
    s1 = P[(size_t)n * OFEAT + j0 + 1];
  }
  float inv = 1.0f / fmaxf(RSUM[n], 1e-12f);
  float x0 = s0 * inv + b1[j0];
  float x1 = s1 * inv + b1[j0 + 1];
  float m = fmaxf(x0, x1);
#pragma unroll
  for (int o = 32; o; o >>= 1) m = fmaxf(m, __shfl_xor(m, o));
  float e = expf(x0 - m) + expf(x1 - m);
#pragma unroll
  for (int o = 32; o; o >>= 1) e += __shfl_xor(e, o);
  float lse = m + logf(e);
  out[(size_t)n * OFEAT + j0]     = x0 - lse;
  out[(size_t)n * OFEAT + j0 + 1] = x1 - lse;
}

extern "C" void kernel_launch(void* const* d_in, const int* in_sizes, int n_in,
                              void* d_out, int out_size, void* d_ws, size_t ws_size,
                              hipStream_t stream) {
  const float* stru = (const float*)d_in[0];
  const float* mm   = (const float*)d_in[1];
  const float* glw  = (const float*)d_in[2];
  const float* w0   = (const float*)d_in[3];
  const float* b0   = (const float*)d_in[4];
  const float* w1   = (const float*)d_in[5];
  const float* b1   = (const float*)d_in[6];
  float* out = (float*)d_out;

  char* ws = (char*)d_ws;
  size_t off = 0;
  auto carve = [&](size_t bytes) -> void* {
    void* p = ws + off;
    off += (bytes + 255) & ~(size_t)255;
    return p;
  };
  u16*   G     = (u16*)carve((size_t)NNODES * KG * 2);        // 12.6 MB
  u16*   EMB   = (u16*)carve((size_t)NNODES * DIM * 2);       // 3.1 MB
  u16*   W0T   = (u16*)carve((size_t)NHID * DIM * 2);
  u16*   W1T   = (u16*)carve((size_t)OFEAT * DIM * 2);
  u16*   ADJ   = (u16*)carve((size_t)NNODES * NNODES * 2);    // 75.5 MB
  u16*   X0T   = (u16*)carve((size_t)NHID * NNODES * 2);      // 3.1 MB
  u16*   H     = (u16*)carve((size_t)NNODES * NHID * 2);      // 3.1 MB
  u16*   HW1T  = (u16*)carve((size_t)OFEAT * NNODES * 2);     // 1.6 MB
  float* RSUM  = (float*)carve((size_t)NNODES * 4);           // 24 KB

  // remaining workspace -> bf16 split-K partial slices
  const size_t slice1b = (size_t)NNODES * NHID * 2;   // 3.15 MB (bf16)
  const size_t slice2b = (size_t)NNODES * OFEAT * 2;  // 1.57 MB (bf16)
  size_t avail = (ws_size > off) ? (ws_size - off) : 0;
  char* P = ws + off;

  const int zc1[6] = {8, 6, 4, 3, 2, 1};
  const int zc2[8] = {16, 12, 8, 6, 4, 3, 2, 1};
  int z1 = 1, z2 = 1;
  for (int i = 0; i < 6; ++i) if ((size_t)zc1[i] * slice1b <= avail) { z1 = zc1[i]; break; }
  for (int i = 0; i < 8; ++i) if ((size_t)zc2[i] * slice2b <= avail) { z2 = zc2[i]; break; }
  const bool part1 = (z1 >= 4);
  const bool part2 = (z2 >= 4);
  void* P1 = P;                              // partial: z1 bf16 slices; atomic: f32
  void* P2 = P;                              // reused after reduce1 consumes P1

  build_g<<<NNODES, 256, 0, stream>>>(stru, mm, glw, w0, w1, G, EMB, W0T, W1T, RSUM);

  // S = G*G^T (1176 blocks, no rowsum) + X0T weight GEMM (96 tail blocks).
  gemm_sym_x0<<<1176 + 96, 256, 0, stream>>>(G, EMB, W0T, ADJ, X0T);

  // hop1: OUT1 = raw_adj @ X0 + fused ADJ rowsums. 64x256 tiles, K=6144 split.
  if (part1) {
    gemm_hop1<false><<<dim3(1, 96, z1), 256, 0, stream>>>(ADJ, X0T, P1, RSUM, NNODES, NNODES,
                                                          NNODES / z1, (size_t)NNODES * NHID);
    reduce1<true><<<NNODES / 2, 256, 0, stream>>>(P1, z1, RSUM, b0, H);
  } else {
    hipMemsetAsync(P1, 0, (size_t)NNODES * NHID * 4, stream);
    gemm_hop1<true><<<dim3(1, 96, 8), 256, 0, stream>>>(ADJ, X0T, P1, RSUM, NNODES, NNODES,
                                                        NNODES / 8, 0);
    reduce1<false><<<NNODES / 2, 256, 0, stream>>>(P1, 1, RSUM, b0, H);
  }

  // HW1T[j][node] = sum_d W1T[j][d]*H[node][d]
  gemm_nt<<<dim3(48, 1, 1), 256, 0, stream>>>(W1T, H, HW1T, NNODES, DIM, DIM, DIM);

  // hop2: OUT2 = raw_adj @ HW1. 128x128 tiles, K=6144 split.
  if (part2) {
    gemm_hop2<false><<<dim3(1, 48, z2), 256, 0, stream>>>(ADJ, HW1T, P2, NNODES, NNODES,
                                                          NNODES / z2, (size_t)NNODES * OFEAT);
    reduce2<true><<<NNODES / 4, 256, 0, stream>>>(P2, z2, RSUM, b1, out);
  } else {
    hipMemsetAsync(P2, 0, (size_t)NNODES * OFEAT * 4, stream);   // after P1 consumed
    gemm_hop2<true><<<dim3(1, 48, 16), 256, 0, stream>>>(ADJ, HW1T, P2, NNODES, NNODES,
                                                         NNODES / 16, 0);
    reduce2<false><<<NNODES / 4, 256, 0, stream>>>(P2, 1, RSUM, b1, out);
  }

  (void)in_sizes; (void)n_in; (void)out_size;
}